// Round 1
// baseline (226.633 us; speedup 1.0000x reference)
//
#include <hip/hip_runtime.h>

// Depth-3 Haar wavelet packet transform along last dim (S=8192), rows = B*C = 4096.
// out[row, n*1024 + j] = c^3 * sum_t (-1)^(b1*t0 + b2*t1 + b3*t2) x[row, 8j+t],
// n = 4*b1 + 2*b2 + b3, c^3 = 2^{-1.5}.
//
// LDS-free formulation: the 8-point transform is local to 8 consecutive inputs,
// so one thread owns inputs [8g, 8g+8) (two float4 loads, 32B/lane) and computes
// all 8 node outputs in-register. Consecutive threads own consecutive j, so each
// per-node scalar store is a contiguous 256B-per-wave global_store_dword.
// No LDS, no shuffles, no barrier -> pure stream, same shape as a fill kernel.

#define C3 0.35355339059327373f

__global__ __launch_bounds__(256) void swpt3_kernel(const float4* __restrict__ x,
                                                    float* __restrict__ out) {
    const unsigned g = blockIdx.x * 256u + threadIdx.x;   // one thread per 8 inputs

    const float4 va = x[(size_t)g * 2u];
    const float4 vb = x[(size_t)g * 2u + 1u];

    // level 1 (combine t0): sums s*, diffs d*
    const float s0 = va.x + va.y, d0 = va.x - va.y;
    const float s1 = va.z + va.w, d1 = va.z - va.w;
    const float s2 = vb.x + vb.y, d2 = vb.x - vb.y;
    const float s3 = vb.z + vb.w, d3 = vb.z - vb.w;
    // level 2 (combine t1)
    const float ss0 = s0 + s1, sd0 = s0 - s1;
    const float ss1 = s2 + s3, sd1 = s2 - s3;
    const float ds0 = d0 + d1, dd0 = d0 - d1;
    const float ds1 = d2 + d3, dd1 = d2 - d3;
    // level 3 (combine t2) + scale; node n = 4*b1 + 2*b2 + b3
    const float r0 = (ss0 + ss1) * C3;
    const float r1 = (ss0 - ss1) * C3;
    const float r2 = (sd0 + sd1) * C3;
    const float r3 = (sd0 - sd1) * C3;
    const float r4 = (ds0 + ds1) * C3;
    const float r5 = (ds0 - ds1) * C3;
    const float r6 = (dd0 + dd1) * C3;
    const float r7 = (dd0 - dd1) * C3;

    const unsigned row = g >> 10;          // 1024 threads per row (8192/8)
    const unsigned j   = g & 1023u;
    float* o = out + (size_t)row * 8192u + j;
    o[0]        = r0;
    o[1024u]    = r1;
    o[2048u]    = r2;
    o[3072u]    = r3;
    o[4096u]    = r4;
    o[5120u]    = r5;
    o[6144u]    = r6;
    o[7168u]    = r7;
}

extern "C" void kernel_launch(void* const* d_in, const int* in_sizes, int n_in,
                              void* d_out, int out_size, void* d_ws, size_t ws_size,
                              hipStream_t stream) {
    const float4* x = (const float4*)d_in[0];
    float* out = (float*)d_out;
    // 64*64*8192 floats / 8 per thread = 4,194,304 threads = 16384 blocks x 256.
    swpt3_kernel<<<16384, 256, 0, stream>>>(x, out);
}